// Round 1
// baseline (203.001 us; speedup 1.0000x reference)
//
#include <hip/hip_runtime.h>
#include <math.h>

#define BB 32
#define SS 8192
#define DD 512
#define D4 (DD / 4)  // 128

static constexpr float AGE_PEN = 0.02f;
static constexpr float MIN_STR = 0.001f;
static constexpr float STR_BOOST = 0.5f;
static constexpr float RMS_EPS_F = 1e-6f;

// ---- block reduction helpers (256-thread blocks = 4 waves) ----
__device__ inline float block_sum(float v, volatile float* red) {
    int tid = threadIdx.x, lane = tid & 63, wid = tid >> 6;
#pragma unroll
    for (int off = 32; off; off >>= 1) v += __shfl_xor(v, off);
    if (lane == 0) red[wid] = v;
    __syncthreads();
    if (tid == 0) {
        float t = 0.f;
        int nw = blockDim.x >> 6;
        for (int i = 0; i < nw; i++) t += red[i];
        red[0] = t;
    }
    __syncthreads();
    float r = red[0];
    __syncthreads();
    return r;
}

__device__ inline float block_max(float v, volatile float* red) {
    int tid = threadIdx.x, lane = tid & 63, wid = tid >> 6;
#pragma unroll
    for (int off = 32; off; off >>= 1) v = fmaxf(v, __shfl_xor(v, off));
    if (lane == 0) red[wid] = v;
    __syncthreads();
    if (tid == 0) {
        float t = -1e30f;
        int nw = blockDim.x >> 6;
        for (int i = 0; i < nw; i++) t = fmaxf(t, red[i]);
        red[0] = t;
    }
    __syncthreads();
    float r = red[0];
    __syncthreads();
    return r;
}

// ---- kernel 1: qn[b,d] = q[b,d] / (||q[b]|| + 1e-6) ----
__global__ __launch_bounds__(256) void qn_kernel(const float* __restrict__ q,
                                                 float* __restrict__ qn) {
    __shared__ float red[8];
    int b = blockIdx.x, tid = threadIdx.x;
    const float* row = q + b * DD;
    float v0 = row[tid], v1 = row[tid + 256];
    float ss = block_sum(v0 * v0 + v1 * v1, red);
    float inv = 1.f / (sqrtf(ss) + 1e-6f);
    qn[b * DD + tid] = v0 * inv;
    qn[b * DD + tid + 256] = v1 * inv;
}

// ---- kernel 2: logits. one wave per (b,s) row; 4 rows per 256-thread block ----
__global__ __launch_bounds__(256) void logits_kernel(const float4* __restrict__ keys,
                                                     const float* __restrict__ qn,
                                                     const float* __restrict__ age,
                                                     const float* __restrict__ strength,
                                                     float* __restrict__ logits) {
    int wid = threadIdx.x >> 6, lane = threadIdx.x & 63;
    int row = blockIdx.x * 4 + wid;          // < BB*SS = 262144
    int b = row >> 13;                        // row / SS
    const float4* k = keys + (long long)row * D4;
    const float4* q4 = (const float4*)qn + b * D4;

    float4 k0 = k[lane], k1 = k[lane + 64];
    float4 q0 = q4[lane], q1 = q4[lane + 64];

    float kk = k0.x * k0.x + k0.y * k0.y + k0.z * k0.z + k0.w * k0.w +
               k1.x * k1.x + k1.y * k1.y + k1.z * k1.z + k1.w * k1.w;
    float kq = k0.x * q0.x + k0.y * q0.y + k0.z * q0.z + k0.w * q0.w +
               k1.x * q1.x + k1.y * q1.y + k1.z * q1.z + k1.w * q1.w;
#pragma unroll
    for (int off = 32; off; off >>= 1) {
        kk += __shfl_xor(kk, off);
        kq += __shfl_xor(kq, off);
    }
    if (lane == 0) {
        float st = strength[row];
        float a = age[row];
        float sim = kq / (sqrtf(kk) + 1e-6f);
        float lg = sim + STR_BOOST * logf(fminf(fmaxf(st, MIN_STR), 1e9f)) - AGE_PEN * a;
        if (!(st > MIN_STR)) lg -= 1000.f;
        logits[row] = lg;
    }
}

// ---- kernel 3: softmax over S per batch row; one block per b ----
__global__ __launch_bounds__(256) void softmax_kernel(const float* __restrict__ logits,
                                                      float* __restrict__ w) {
    __shared__ float red[8];
    int b = blockIdx.x, tid = threadIdx.x;
    const float4* lg4 = (const float4*)(logits + b * SS);
    float4* w4 = (float4*)(w + b * SS);

    float4 loc[8];
    float mx = -1e30f;
#pragma unroll
    for (int i = 0; i < 8; i++) {
        float4 v = lg4[tid + i * 256];
        loc[i] = v;
        mx = fmaxf(mx, fmaxf(fmaxf(v.x, v.y), fmaxf(v.z, v.w)));
    }
    mx = block_max(mx, red);

    float sum = 0.f;
#pragma unroll
    for (int i = 0; i < 8; i++) {
        float4 v = loc[i];
        v.x = expf(v.x - mx);
        v.y = expf(v.y - mx);
        v.z = expf(v.z - mx);
        v.w = expf(v.w - mx);
        sum += v.x + v.y + v.z + v.w;
        loc[i] = v;
    }
    sum = block_sum(sum, red);
    float inv = 1.f / sum;
#pragma unroll
    for (int i = 0; i < 8; i++) {
        float4 v = loc[i];
        v.x *= inv; v.y *= inv; v.z *= inv; v.w *= inv;
        w4[tid + i * 256] = v;
    }
}

// ---- kernel 4: partial weighted sums over 128-slot chunks ----
// grid = (64 chunks, B), block = 128 threads (one float4 column each)
__global__ __launch_bounds__(128) void wsum_kernel(const float4* __restrict__ vals,
                                                   const float* __restrict__ w,
                                                   float4* __restrict__ partial) {
    __shared__ float sw[128];
    int chunk = blockIdx.x, b = blockIdx.y, tid = threadIdx.x;
    int s0 = chunk * 128;
    sw[tid] = w[b * SS + s0 + tid];
    __syncthreads();

    const float4* vbase = vals + ((long long)b * SS + s0) * D4 + tid;
    float4 acc = {0.f, 0.f, 0.f, 0.f};
#pragma unroll 4
    for (int s = 0; s < 128; s++) {
        float4 v = vbase[(long long)s * D4];
        float ww = sw[s];
        acc.x += ww * v.x;
        acc.y += ww * v.y;
        acc.z += ww * v.z;
        acc.w += ww * v.w;
    }
    partial[(b * 64 + chunk) * D4 + tid] = acc;
}

// ---- kernel 5: reduce partials + RMSNorm; one block per b ----
__global__ __launch_bounds__(256) void reduce_rms_kernel(const float* __restrict__ partial,
                                                         const float* __restrict__ scale,
                                                         float* __restrict__ readout) {
    __shared__ float red[8];
    int b = blockIdx.x, tid = threadIdx.x;
    const float* p = partial + (long long)b * 64 * DD;
    float r0 = 0.f, r1 = 0.f;
#pragma unroll 4
    for (int c = 0; c < 64; c++) {
        r0 += p[c * DD + tid];
        r1 += p[c * DD + tid + 256];
    }
    float ss = block_sum(r0 * r0 + r1 * r1, red);
    float rms = sqrtf(ss / (float)DD + RMS_EPS_F);
    float inv = 1.f / rms;
    readout[b * DD + tid] = r0 * inv * scale[tid];
    readout[b * DD + tid + 256] = r1 * inv * scale[tid + 256];
}

extern "C" void kernel_launch(void* const* d_in, const int* in_sizes, int n_in,
                              void* d_out, int out_size, void* d_ws, size_t ws_size,
                              hipStream_t stream) {
    const float* q        = (const float*)d_in[0];
    const float* keys     = (const float*)d_in[1];
    const float* vals     = (const float*)d_in[2];
    const float* age      = (const float*)d_in[3];
    const float* strength = (const float*)d_in[4];
    const float* scale    = (const float*)d_in[5];

    float* out = (float*)d_out;
    float* readout = out;                    // [B, D]   = 16384
    float* w       = out + BB * DD;          // [B, S]   = 262144
    float* logits  = out + BB * DD + BB * SS; // [B, S]  = 262144

    float* ws = (float*)d_ws;
    float* qn = ws;                          // B*D = 16384 floats
    float* partial = ws + BB * DD;           // B*64*D = 1,048,576 floats

    qn_kernel<<<BB, 256, 0, stream>>>(q, qn);
    logits_kernel<<<BB * SS / 4, 256, 0, stream>>>((const float4*)keys, qn, age, strength, logits);
    softmax_kernel<<<BB, 256, 0, stream>>>(logits, w);
    wsum_kernel<<<dim3(64, BB), 128, 0, stream>>>((const float4*)vals, w, (float4*)partial);
    reduce_rms_kernel<<<BB, 256, 0, stream>>>(partial, scale, readout);
}